// Round 13
// baseline (380.435 us; speedup 1.0000x reference)
//
#include <hip/hip_runtime.h>

typedef unsigned long long u64;
typedef _Float16 f16;
typedef f16 f16x8 __attribute__((ext_vector_type(8)));
typedef f16 f16x4 __attribute__((ext_vector_type(4)));
typedef float f32x16 __attribute__((ext_vector_type(16)));

#define TOK 16384
#define KK 8192
#define DD 256

#define BM 128
#define BN 128
#define BK 32
#define NT 8          // DD/BK K-tiles

#define SCALE 4096.0f                 // 2^12, exact
#define DESCALE (1.0f/8388608.0f)     // 2^-23 = 2^-24 (limb^2) * 2 (ref's 2*dot)

// ---------------- e2[k] = sum_d emb[d][k]^2 (+ counts/nsum init folded) --------
__global__ void vq_e2_kernel(const float* __restrict__ emb, float* __restrict__ e2,
                             int* __restrict__ counts, float* __restrict__ nsum) {
    int k = blockIdx.x * 256 + threadIdx.x;          // 32 blocks
    float s = 0.0f;
    for (int d = 0; d < DD; d++) {
        float v = emb[(size_t)d * KK + k];
        s = fmaf(v, v, s);
    }
    e2[k] = s;
    counts[k] = 0;
    if (k == 0) *nsum = 0.0f;
}

// ------- fused: x2[t] + limb split of x into unit-major panels ---------------
// Panel layout: Ah/Al[kt][u][16384 rows][8 f16]; element (t,d): kt=d>>5,
// u=(d>>3)&3, j=d&7. Staging in argmin then reads contiguous 16B cells.
__global__ void vq_x2split_kernel(const float* __restrict__ x, float* __restrict__ x2,
                                  f16* __restrict__ Ah, f16* __restrict__ Al,
                                  float* __restrict__ sums, u64* __restrict__ best) {
    int gid = blockIdx.x * 256 + threadIdx.x;        // 4096 blocks
    sums[gid] = 0.0f;
    sums[gid + 1048576] = 0.0f;
    if (gid < TOK) best[gid] = 0xFFFFFFFFFFFFFFFFULL;
    int t = gid >> 6;                                // wave per token
    int lane = threadIdx.x & 63;
    float4 v = *(const float4*)(x + (size_t)t * DD + lane * 4);
    f16x4 h, l;
    float s;
    s = v.x * SCALE; h.x = (f16)s; l.x = (f16)(s - (float)h.x);
    s = v.y * SCALE; h.y = (f16)s; l.y = (f16)(s - (float)h.y);
    s = v.z * SCALE; h.z = (f16)s; l.z = (f16)(s - (float)h.z);
    s = v.w * SCALE; h.w = (f16)s; l.w = (f16)(s - (float)h.w);
    int kt = lane >> 3;                              // d = lane*4
    int u  = (lane >> 1) & 3;
    int jj = (lane & 1) * 4;
    size_t o = ((size_t)(kt * 4 + u) * 16384 + t) * 8 + jj;
    *(f16x4*)(Ah + o) = h;
    *(f16x4*)(Al + o) = l;
    float p = v.x * v.x + v.y * v.y + v.z * v.z + v.w * v.w;
#pragma unroll
    for (int off = 32; off > 0; off >>= 1) p += __shfl_down(p, off, 64);
    if (lane == 0) x2[t] = p;
}

// ---- transpose emb -> embT (fp32) + limb split -> unit-major B panels -------
// Bh/Bl[kt][u][8192 k-rows][8 f16]
__global__ void vq_trsplit_kernel(const float* __restrict__ emb, float* __restrict__ embT,
                                  f16* __restrict__ Bh, f16* __restrict__ Bl) {
    __shared__ float tile[32][33];
    int tx = threadIdx.x & 31, ty = threadIdx.x >> 5;    // 32x8 threads
    int k0 = blockIdx.x * 32, d0 = blockIdx.y * 32;      // grid (256, 8)
#pragma unroll
    for (int j = 0; j < 4; j++) {
        int d = ty * 4 + j;
        tile[d][tx] = emb[(size_t)(d0 + d) * KK + k0 + tx];
    }
    __syncthreads();
#pragma unroll
    for (int j = 0; j < 4; j++) {
        int k = ty * 4 + j;
        float v = tile[tx][k];
        embT[(size_t)(k0 + k) * DD + d0 + tx] = v;
        float sv = v * SCALE;
        f16 h = (f16)sv;
        int d = d0 + tx;
        int kt = d >> 5, u = (d >> 3) & 3, jj = d & 7;
        size_t o = ((size_t)(kt * 4 + u) * 8192 + (k0 + k)) * 8 + jj;
        Bh[o] = h;
        Bl[o] = (f16)(sv - (float)h);
    }
}

// global->LDS 16B, offset baked into pointer (r11 lesson: never use the
// builtin's offset immediate).
__device__ __forceinline__ void gl(const char* g, char* l) {
    __builtin_amdgcn_global_load_lds(
        (const __attribute__((address_space(1))) unsigned int*)g,
        (__attribute__((address_space(3))) unsigned int*)l, 16, 0, 0);
}

// ---------------- fused distance + argmin: 128x128, 32x32x16, unit-major -----
// r7 chassis (2 barriers/K-tile). LDS tiles [4 units][128 rows][16B] per
// operand; staging = contiguous coalesced 2KB runs (global panels pre-arranged
// unit-major); fragment reads = contiguous 512B per half-wave -> bank-floor,
// no swizzle. 24 x mfma_f32_32x32x16_f16 per wave per K-tile (vs 48 16x16):
// halves MFMA issue slots, ceiling 2075->2382 TF. Product order hh, hl, lh
// (r5-verified numerics class, absmax~64).
__global__ __launch_bounds__(256, 2) void vq_argmin_kernel(
        const f16* __restrict__ Ah, const f16* __restrict__ Al,
        const f16* __restrict__ Bh, const f16* __restrict__ Bl,
        const float* __restrict__ x2, const float* __restrict__ e2,
        u64* __restrict__ best) {
    __shared__ char lds[32768 + 1024];     // 4 x 8KB unit-major tiles + red[128]

    const int tid = threadIdx.x;
    const int lane = tid & 63;
    const int wid = tid >> 6;              // 4 waves: 2x2 over 128x128
    const int wrow = (wid >> 1) * 64;
    const int wcol = (wid & 1) * 64;
    const int lane31 = lane & 31;
    const int hi = lane >> 5;
    const int k0 = blockIdx.x * BN;        // grid (64, 128)
    const int t0 = blockIdx.y * BM;

    // staging: op {0:Ah,1:Al,2:Bh,3:Bl} x issue h; cell = h*256+tid,
    // u = cell>>7, row = cell&127. Global = base + (u*NR + r0 + row)*16,
    // + j*(4*NR*16) per K-tile. LDS dest = op*8192 + cell*16 (linear).
    const char* gaddr[8];
    int laddr[8];
#pragma unroll
    for (int is = 0; is < 8; is++) {
        const int op = is >> 1;
        int cell = (is & 1) * 256 + tid;
        int u = cell >> 7, rw = cell & 127;
        const char* base = (op == 0) ? (const char*)Ah : (op == 1) ? (const char*)Al
                         : (op == 2) ? (const char*)Bh : (const char*)Bl;
        const size_t NR = (op < 2) ? 16384 : 8192;
        const int r0 = (op < 2) ? t0 : k0;
        gaddr[is] = base + ((size_t)u * NR + r0 + rw) * 16;
        laddr[is] = op * 8192 + cell * 16;
    }

#define MF32(a, b, c) __builtin_amdgcn_mfma_f32_32x32x16_f16(a, b, c, 0, 0, 0)

    f32x16 acc[2][2];
#pragma unroll
    for (int ci = 0; ci < 2; ci++)
#pragma unroll
        for (int cj = 0; cj < 2; cj++)
#pragma unroll
            for (int r = 0; r < 16; r++) acc[ci][cj][r] = 0.0f;

    u64* red = (u64*)(lds + 32768);
    if (tid < BM) red[tid] = 0xFFFFFFFFFFFFFFFFULL;

    // frag read bases: row = wrow/wcol + ci*32 + lane31, unit = s*2 + hi
    const int abase = (wrow + lane31) * 16 + hi * 2048;   // + ci*512 + s*4096
    const int bbase = (wcol + lane31) * 16 + hi * 2048;   // + cj*512 + s*4096

    for (int j = 0; j < NT; j++) {
        const size_t dA = (size_t)j << 20;      // j * 4*16384*16
        const size_t dB = (size_t)j << 19;      // j * 4*8192*16
        __syncthreads();                        // prev tile's reads complete
#pragma unroll
        for (int is = 0; is < 8; is++)
            gl(gaddr[is] + ((is >> 1) < 2 ? dA : dB), lds + laddr[is]);
        __syncthreads();                        // drain: tile j in LDS

        f16x8 axh[2][2], axl[2][2], beh[2][2], bel[2][2];
#pragma unroll
        for (int ci = 0; ci < 2; ci++)
#pragma unroll
            for (int s = 0; s < 2; s++)
                axh[ci][s] = *(const f16x8*)(lds + abase + ci * 512 + s * 4096);
#pragma unroll
        for (int cj = 0; cj < 2; cj++)
#pragma unroll
            for (int s = 0; s < 2; s++)
                beh[cj][s] = *(const f16x8*)(lds + 16384 + bbase + cj * 512 + s * 4096);
        __builtin_amdgcn_s_setprio(1);
#pragma unroll
        for (int ci = 0; ci < 2; ci++)
#pragma unroll
            for (int cj = 0; cj < 2; cj++)
#pragma unroll
                for (int s = 0; s < 2; s++)
                    acc[ci][cj] = MF32(axh[ci][s], beh[cj][s], acc[ci][cj]);
        __builtin_amdgcn_s_setprio(0);

#pragma unroll
        for (int cj = 0; cj < 2; cj++)
#pragma unroll
            for (int s = 0; s < 2; s++)
                bel[cj][s] = *(const f16x8*)(lds + 24576 + bbase + cj * 512 + s * 4096);
        __builtin_amdgcn_s_setprio(1);
#pragma unroll
        for (int ci = 0; ci < 2; ci++)
#pragma unroll
            for (int cj = 0; cj < 2; cj++)
#pragma unroll
                for (int s = 0; s < 2; s++)
                    acc[ci][cj] = MF32(axh[ci][s], bel[cj][s], acc[ci][cj]);
        __builtin_amdgcn_s_setprio(0);

#pragma unroll
        for (int ci = 0; ci < 2; ci++)
#pragma unroll
            for (int s = 0; s < 2; s++)
                axl[ci][s] = *(const f16x8*)(lds + 8192 + abase + ci * 512 + s * 4096);
        __builtin_amdgcn_s_setprio(1);
#pragma unroll
        for (int ci = 0; ci < 2; ci++)
#pragma unroll
            for (int cj = 0; cj < 2; cj++)
#pragma unroll
                for (int s = 0; s < 2; s++)
                    acc[ci][cj] = MF32(axl[ci][s], beh[cj][s], acc[ci][cj]);
        __builtin_amdgcn_s_setprio(0);
    }

    // ---------------- epilogue: distances + argmin ----------------
    // 32x32 C/D (m74/m101, r5-verified): col = lane&31,
    // row = (r&3) + 8*(r>>2) + 4*hi.
    __syncthreads();

    float se2[2];
#pragma unroll
    for (int cj = 0; cj < 2; cj++) se2[cj] = e2[k0 + wcol + cj * 32 + lane31];

#pragma unroll
    for (int ci = 0; ci < 2; ci++) {
#pragma unroll
        for (int r = 0; r < 16; r++) {
            int rowl = wrow + ci * 32 + (r & 3) + 8 * (r >> 2) + 4 * hi;
            float sx2 = x2[t0 + rowl];
            u64 b = 0xFFFFFFFFFFFFFFFFULL;
#pragma unroll
            for (int cj = 0; cj < 2; cj++) {
                int col = k0 + wcol + cj * 32 + lane31;
                float s = sx2 + se2[cj];             // rounded add (matches ref)
                float td = acc[ci][cj][r] * DESCALE; // exact pow2 scale
                asm volatile("" : "+v"(td));
                float dist = s - td;                 // rounded sub (matches ref)
                u64 pk = ((u64)__float_as_uint(dist) << 32) | (unsigned)col;
                b = pk < b ? pk : b;
            }
#pragma unroll
            for (int m = 1; m < 32; m <<= 1) {
                u64 o = __shfl_xor(b, m, 64);
                b = o < b ? o : b;
            }
            if (lane31 == 0) atomicMin(&red[rowl], b);
        }
    }
    __syncthreads();
    if (tid < BM) atomicMin(&best[t0 + tid], red[tid]);
}

// ---------------- extract indices + counts ----------------
__global__ void vq_indices_kernel(const u64* __restrict__ best, int* __restrict__ indices,
                                  int* __restrict__ counts) {
    int t = blockIdx.x * 256 + threadIdx.x;
    int idx = (int)(best[t] & 0xFFFFFFFFULL);
    indices[t] = idx;
    atomicAdd(&counts[idx], 1);
}

// ---------------- new_N + N_sum ----------------
__global__ void vq_newN_kernel(const float* __restrict__ N, const int* __restrict__ counts,
                               float* __restrict__ outN, float* __restrict__ nsum) {
    int k = blockIdx.x * 256 + threadIdx.x;
    float a = 0.99f * N[k];
    float b = 0.01f * (float)counts[k];
    float nN = a + b;
    outN[k] = nN;
    float s = nN;
#pragma unroll
    for (int off = 32; off > 0; off >>= 1) s += __shfl_down(s, off, 64);
    __shared__ float wsum[4];
    int lane = threadIdx.x & 63, w = threadIdx.x >> 6;
    if (lane == 0) wsum[w] = s;
    __syncthreads();
    if (threadIdx.x == 0) atomicAdd(nsum, wsum[0] + wsum[1] + wsum[2] + wsum[3]);
}

// ---------------- fused: quantized_st write + sums scatter ----------------
__global__ void vq_gs_kernel(const float* __restrict__ x, const float* __restrict__ embT,
                             const int* __restrict__ indices, float* __restrict__ out0,
                             float* __restrict__ sums) {
    int t = blockIdx.x * 4 + (threadIdx.x >> 6);     // 4096 blocks, wave per token
    int lane = threadIdx.x & 63;
    int idx = indices[t];
    size_t o = (size_t)t * DD + lane * 4;
    float4 xv = *(const float4*)(x + o);
    float4 qv = *(const float4*)(embT + (size_t)idx * DD + lane * 4);
    float4 ov;
    ov.x = xv.x + (qv.x - xv.x);
    ov.y = xv.y + (qv.y - xv.y);
    ov.z = xv.z + (qv.z - xv.z);
    ov.w = xv.w + (qv.w - xv.w);
    *(float4*)(out0 + o) = ov;
    float* base = sums + (size_t)idx * DD + lane * 4;
    atomicAdd(base + 0, xv.x);
    atomicAdd(base + 1, xv.y);
    atomicAdd(base + 2, xv.z);
    atomicAdd(base + 3, xv.w);
}

// ---------------- new_m and new_embeddings ----------------
__global__ void vq_final_kernel(const float* __restrict__ m, const float* __restrict__ sums,
                                const float* __restrict__ outN, const float* __restrict__ nsum,
                                float* __restrict__ outEmb, float* __restrict__ outM) {
    int gid = blockIdx.x * 256 + threadIdx.x;
    int k = gid & (KK - 1);
    int d = gid >> 13;
    float Nsum = *nsum;
    float nN = outN[k];
    float scaled = (nN + 1e-5f) / (Nsum + 0.08192f) * Nsum;
    float a = 0.99f * m[gid];
    float b = 0.01f * sums[(size_t)k * DD + d];
    float mv = a + b;
    outM[gid] = mv;
    outEmb[gid] = mv / scaled;
}

extern "C" void kernel_launch(void* const* d_in, const int* in_sizes, int n_in,
                              void* d_out, int out_size, void* d_ws, size_t ws_size,
                              hipStream_t stream) {
    const float* x   = (const float*)d_in[0];   // [16384][256]
    const float* emb = (const float*)d_in[1];   // [256][8192]
    const float* Nin = (const float*)d_in[2];   // [8192]
    const float* min = (const float*)d_in[3];   // [256][8192]

    float* out0   = (float*)d_out;              // quantized_st  [4194304]
    float* outEmb = out0 + 4194304;             // new_embeddings [2097152]
    float* outN   = outEmb + 2097152;           // new_N [8192]
    float* outM   = outN + 8192;                // new_m [2097152]

    // workspace (floats)
    float* ws      = (float*)d_ws;
    float* sums    = ws;                        // 2097152
    float* e2buf   = ws + 2097152;              // 8192
    float* x2buf   = e2buf + 8192;              // 16384
    u64*   best    = (u64*)(x2buf + 16384);     // 16384 u64
    int*   idxbuf  = (int*)(best + 16384);      // 16384
    int*   counts  = idxbuf + 16384;            // 8192
    float* nsum    = (float*)(counts + 8192);   // 1

    // unit-major fp16 limb panels staged in output regions written later:
    f16* Ahb = (f16*)out0;                      // 8 MB
    f16* Alb = Ahb + 4194304;                   // 8 MB (out0 is 16 MB)
    f16* Bhb = (f16*)outEmb;                    // 4 MB
    f16* Blb = Bhb + 2097152;                   // 4 MB (outEmb is 8 MB)
    float* embT = outM;                         // 8 MB, overwritten by vq_final last

    vq_e2_kernel<<<32, 256, 0, stream>>>(emb, e2buf, counts, nsum);
    vq_x2split_kernel<<<4096, 256, 0, stream>>>(x, x2buf, Ahb, Alb, sums, best);
    vq_trsplit_kernel<<<dim3(256, 8), 256, 0, stream>>>(emb, embT, Bhb, Blb);
    vq_argmin_kernel<<<dim3(KK / BN, TOK / BM), 256, 0, stream>>>(
        Ahb, Alb, Bhb, Blb, x2buf, e2buf, best);
    vq_indices_kernel<<<64, 256, 0, stream>>>(best, idxbuf, counts);
    vq_newN_kernel<<<32, 256, 0, stream>>>(Nin, counts, outN, nsum);
    vq_gs_kernel<<<4096, 256, 0, stream>>>(x, embT, idxbuf, out0, sums);
    vq_final_kernel<<<8192, 256, 0, stream>>>(min, sums, outN, nsum, outEmb, outM);
}

// Round 14
// 308.551 us; speedup vs baseline: 1.2330x; 1.2330x over previous
//
#include <hip/hip_runtime.h>

typedef unsigned long long u64;
typedef _Float16 f16;
typedef f16 f16x8 __attribute__((ext_vector_type(8)));
typedef f16 f16x4 __attribute__((ext_vector_type(4)));
typedef float f32x4 __attribute__((ext_vector_type(4)));

#define TOK 16384
#define KK 8192
#define DD 256

#define BM 128
#define BN 128
#define BK 32
#define NT 8          // DD/BK K-tiles

#define SCALE 4096.0f                 // 2^12, exact
#define DESCALE (1.0f/8388608.0f)     // 2^-23 = 2^-24 (limb^2) * 2 (ref's 2*dot)

// ------- fused: x2[t] + fp16 limb split of x (+ sums/best init) -------
__global__ void vq_x2split_kernel(const float* __restrict__ x, float* __restrict__ x2,
                                  f16* __restrict__ xh, f16* __restrict__ xl,
                                  float* __restrict__ sums, u64* __restrict__ best) {
    int gid = blockIdx.x * 256 + threadIdx.x;        // 4096 blocks
    sums[gid] = 0.0f;
    sums[gid + 1048576] = 0.0f;
    if (gid < TOK) best[gid] = 0xFFFFFFFFFFFFFFFFULL;
    int t = gid >> 6;                                // wave per token
    int lane = threadIdx.x & 63;
    size_t o = (size_t)t * DD + lane * 4;
    float4 v = *(const float4*)(x + o);
    f16x4 h, l;
    float s;
    s = v.x * SCALE; h.x = (f16)s; l.x = (f16)(s - (float)h.x);
    s = v.y * SCALE; h.y = (f16)s; l.y = (f16)(s - (float)h.y);
    s = v.z * SCALE; h.z = (f16)s; l.z = (f16)(s - (float)h.z);
    s = v.w * SCALE; h.w = (f16)s; l.w = (f16)(s - (float)h.w);
    *(f16x4*)(xh + o) = h;
    *(f16x4*)(xl + o) = l;
    float p = v.x * v.x + v.y * v.y + v.z * v.z + v.w * v.w;
#pragma unroll
    for (int off = 32; off > 0; off >>= 1) p += __shfl_down(p, off, 64);
    if (lane == 0) x2[t] = p;
}

// ---------------- transpose emb -> embT (fp32) + scaled fp16 limbs ----------------
__global__ void vq_trsplit_kernel(const float* __restrict__ emb, float* __restrict__ embT,
                                  f16* __restrict__ eh, f16* __restrict__ el) {
    __shared__ float tile[32][33];
    int tx = threadIdx.x & 31, ty = threadIdx.x >> 5;    // 32x8 threads
    int k0 = blockIdx.x * 32, d0 = blockIdx.y * 32;      // grid (256, 8)
#pragma unroll
    for (int j = 0; j < 4; j++) {
        int d = ty * 4 + j;
        tile[d][tx] = emb[(size_t)(d0 + d) * KK + k0 + tx];
    }
    __syncthreads();
#pragma unroll
    for (int j = 0; j < 4; j++) {
        int k = ty * 4 + j;
        float v = tile[tx][k];
        size_t o = (size_t)(k0 + k) * DD + d0 + tx;
        embT[o] = v;
        float sv = v * SCALE;
        f16 h = (f16)sv;
        eh[o] = h;
        el[o] = (f16)(sv - (float)h);
    }
}

// ---- e2[k] from embT rows (coalesced float4, wave per k) + counts/nsum init ----
__global__ void vq_e2_kernel(const float* __restrict__ embT, float* __restrict__ e2,
                             int* __restrict__ counts, float* __restrict__ nsum) {
    int k = blockIdx.x * 4 + (threadIdx.x >> 6);     // 2048 blocks, wave per k
    int lane = threadIdx.x & 63;
    float4 v = *(const float4*)(embT + (size_t)k * DD + lane * 4);
    float p = v.x * v.x + v.y * v.y + v.z * v.z + v.w * v.w;
#pragma unroll
    for (int off = 32; off > 0; off >>= 1) p += __shfl_down(p, off, 64);
    if (lane == 0) {
        e2[k] = p;
        counts[k] = 0;
        if (k == 0) *nsum = 0.0f;
    }
}

// ---------------- fused distance + argmin: r7 verbatim (242 us verified) -------
// 128x128 tile, 4 waves, 2 barriers/K-tile, 0-conflict XOR swizzle, per-block
// K-rotation. 851 TF ~ 94% of the m97-structure ceiling.
__global__ __launch_bounds__(256, 2) void vq_argmin_kernel(
        const f16* __restrict__ xh, const f16* __restrict__ xl,
        const f16* __restrict__ eh, const f16* __restrict__ el,
        const float* __restrict__ x2, const float* __restrict__ e2,
        u64* __restrict__ best) {
    __shared__ char lds[32768 + 1024];     // 4 x 8KB operand tiles + red[128] u64

    const int tid = threadIdx.x;
    const int lane = tid & 63;
    const int wid = tid >> 6;              // 4 waves: 2x2 over 128x128
    const int wrow = (wid >> 1) * 64;
    const int wcol = (wid & 1) * 64;
    const int lrow = lane & 15;
    const int kg = lane >> 4;
    const int kgx = ((kg ^ ((lrow >> 1) & 3)) << 4);   // swizzled 16B slot
    const int k0 = blockIdx.x * BN;        // grid (64, 128): k fastest
    const int t0 = blockIdx.y * BM;
    const int bid = blockIdx.x + (blockIdx.y << 6);
    const int off = (bid >> 8) & 3;        // co-resident blocks get distinct offsets

    const char* gb[4];
    gb[0] = (const char*)(xh + (size_t)t0 * DD);
    gb[1] = (const char*)(xl + (size_t)t0 * DD);
    gb[2] = (const char*)(eh + (size_t)k0 * DD);
    gb[3] = (const char*)(el + (size_t)k0 * DD);
    const char* gaddr[8];
    int laddr[8];
#pragma unroll
    for (int is = 0; is < 8; is++) {
        const int u = is >> 1;
        int p = (is & 1) * 4096 + tid * 16;            // 8 KB per operand tile
        int row = p >> 6;
        int slot = (p >> 4) & 3;
        int kgd = slot ^ ((row >> 1) & 3);
        gaddr[is] = gb[u] + (size_t)row * 512 + kgd * 16;
        laddr[is] = u * 8192 + p;
    }

#define GSTAGE(g, l)                                                        \
    __builtin_amdgcn_global_load_lds(                                       \
        (const __attribute__((address_space(1))) unsigned int*)(g),         \
        (__attribute__((address_space(3))) unsigned int*)(l), 16, 0, 0)

    f32x4 acc[4][4];
#pragma unroll
    for (int m = 0; m < 4; m++)
#pragma unroll
        for (int n = 0; n < 4; n++) {
            f32x4 z = {0.0f, 0.0f, 0.0f, 0.0f};
            acc[m][n] = z;
        }

    u64* red = (u64*)(lds + 32768);
    if (tid < BM) red[tid] = 0xFFFFFFFFFFFFFFFFULL;

    for (int jj = 0; jj < NT; jj++) {
        const int j = (jj + off) & 7;          // rotated K-tile schedule
        const int dcb = j * (BK * 2);          // byte offset along rows
        __syncthreads();                       // prev tile's reads complete
#pragma unroll
        for (int is = 0; is < 8; is++) GSTAGE(gaddr[is] + dcb, lds + laddr[is]);
        __syncthreads();                       // drain: tile j in LDS

        f16x8 fxh[4], feh[4], fel[4], fxl[4];
#pragma unroll
        for (int m = 0; m < 4; m++) {
            int row = wrow + m * 16 + lrow;
            fxh[m] = *(const f16x8*)(lds + row * 64 + kgx);
        }
#pragma unroll
        for (int n = 0; n < 4; n++) {
            int row = wcol + n * 16 + lrow;
            feh[n] = *(const f16x8*)(lds + 16384 + row * 64 + kgx);
        }
        __builtin_amdgcn_s_setprio(1);
#pragma unroll
        for (int m = 0; m < 4; m++)
#pragma unroll
            for (int n = 0; n < 4; n++)
                acc[m][n] = __builtin_amdgcn_mfma_f32_16x16x32_f16(fxh[m], feh[n], acc[m][n], 0, 0, 0);
        __builtin_amdgcn_s_setprio(0);

#pragma unroll
        for (int n = 0; n < 4; n++) {
            int row = wcol + n * 16 + lrow;
            fel[n] = *(const f16x8*)(lds + 24576 + row * 64 + kgx);
        }
        __builtin_amdgcn_s_setprio(1);
#pragma unroll
        for (int m = 0; m < 4; m++)
#pragma unroll
            for (int n = 0; n < 4; n++)
                acc[m][n] = __builtin_amdgcn_mfma_f32_16x16x32_f16(fxh[m], fel[n], acc[m][n], 0, 0, 0);
        __builtin_amdgcn_s_setprio(0);

#pragma unroll
        for (int m = 0; m < 4; m++) {
            int row = wrow + m * 16 + lrow;
            fxl[m] = *(const f16x8*)(lds + 8192 + row * 64 + kgx);
        }
        __builtin_amdgcn_s_setprio(1);
#pragma unroll
        for (int m = 0; m < 4; m++)
#pragma unroll
            for (int n = 0; n < 4; n++)
                acc[m][n] = __builtin_amdgcn_mfma_f32_16x16x32_f16(fxl[m], feh[n], acc[m][n], 0, 0, 0);
        __builtin_amdgcn_s_setprio(0);
    }
#undef GSTAGE

    // ---------------- epilogue: distances + argmin ----------------
    // C/D layout: col = lane&15, row = (lane>>4)*4 + reg (m89-verified)
    __syncthreads();

    float se2[4];
#pragma unroll
    for (int n = 0; n < 4; n++) se2[n] = e2[k0 + wcol + n * 16 + lrow];

#pragma unroll
    for (int m = 0; m < 4; m++) {
#pragma unroll
        for (int r = 0; r < 4; r++) {
            int rowl = wrow + m * 16 + kg * 4 + r;
            float sx2 = x2[t0 + rowl];
            u64 b = 0xFFFFFFFFFFFFFFFFULL;
#pragma unroll
            for (int n = 0; n < 4; n++) {
                int kgl = k0 + wcol + n * 16 + lrow;
                float s = sx2 + se2[n];            // rounded add (matches ref)
                float td = acc[m][n][r] * DESCALE; // exact pow2 scale
                asm volatile("" : "+v"(td));
                float dist = s - td;               // rounded sub (matches ref)
                u64 pk = ((u64)__float_as_uint(dist) << 32) | (unsigned)kgl;
                b = pk < b ? pk : b;
            }
#pragma unroll
            for (int off2 = 1; off2 < 16; off2 <<= 1) {
                u64 o = __shfl_xor(b, off2, 64);
                b = o < b ? o : b;
            }
            if (lrow == 0) atomicMin(&red[rowl], b);
        }
    }
    __syncthreads();
    if (tid < BM) atomicMin(&best[t0 + tid], red[tid]);
}

// ---------------- new_N + N_sum ----------------
__global__ void vq_newN_kernel(const float* __restrict__ N, const int* __restrict__ counts,
                               float* __restrict__ outN, float* __restrict__ nsum) {
    int k = blockIdx.x * 256 + threadIdx.x;
    float a = 0.99f * N[k];
    float b = 0.01f * (float)counts[k];
    float nN = a + b;
    outN[k] = nN;
    float s = nN;
#pragma unroll
    for (int off = 32; off > 0; off >>= 1) s += __shfl_down(s, off, 64);
    __shared__ float wsum[4];
    int lane = threadIdx.x & 63, w = threadIdx.x >> 6;
    if (lane == 0) wsum[w] = s;
    __syncthreads();
    if (threadIdx.x == 0) atomicAdd(nsum, wsum[0] + wsum[1] + wsum[2] + wsum[3]);
}

// -------- fused: indices + counts + quantized_st write + sums scatter --------
__global__ void vq_gs_kernel(const float* __restrict__ x, const float* __restrict__ embT,
                             const u64* __restrict__ best, float* __restrict__ out0,
                             float* __restrict__ sums, int* __restrict__ counts) {
    int t = blockIdx.x * 4 + (threadIdx.x >> 6);     // 4096 blocks, wave per token
    int lane = threadIdx.x & 63;
    int idx = (int)(best[t] & 0xFFFFFFFFULL);
    if (lane == 0) atomicAdd(&counts[idx], 1);
    size_t o = (size_t)t * DD + lane * 4;
    float4 xv = *(const float4*)(x + o);
    float4 qv = *(const float4*)(embT + (size_t)idx * DD + lane * 4);
    float4 ov;
    ov.x = xv.x + (qv.x - xv.x);
    ov.y = xv.y + (qv.y - xv.y);
    ov.z = xv.z + (qv.z - xv.z);
    ov.w = xv.w + (qv.w - xv.w);
    *(float4*)(out0 + o) = ov;
    float* base = sums + (size_t)idx * DD + lane * 4;
    atomicAdd(base + 0, xv.x);
    atomicAdd(base + 1, xv.y);
    atomicAdd(base + 2, xv.z);
    atomicAdd(base + 3, xv.w);
}

// ---------------- new_m and new_embeddings ----------------
__global__ void vq_final_kernel(const float* __restrict__ m, const float* __restrict__ sums,
                                const float* __restrict__ outN, const float* __restrict__ nsum,
                                float* __restrict__ outEmb, float* __restrict__ outM) {
    int gid = blockIdx.x * 256 + threadIdx.x;
    int k = gid & (KK - 1);
    int d = gid >> 13;
    float Nsum = *nsum;
    float nN = outN[k];
    float scaled = (nN + 1e-5f) / (Nsum + 0.08192f) * Nsum;
    float a = 0.99f * m[gid];
    float b = 0.01f * sums[(size_t)k * DD + d];
    float mv = a + b;
    outM[gid] = mv;
    outEmb[gid] = mv / scaled;
}

extern "C" void kernel_launch(void* const* d_in, const int* in_sizes, int n_in,
                              void* d_out, int out_size, void* d_ws, size_t ws_size,
                              hipStream_t stream) {
    const float* x   = (const float*)d_in[0];   // [16384][256]
    const float* emb = (const float*)d_in[1];   // [256][8192]
    const float* Nin = (const float*)d_in[2];   // [8192]
    const float* min = (const float*)d_in[3];   // [256][8192]

    float* out0   = (float*)d_out;              // quantized_st  [4194304]
    float* outEmb = out0 + 4194304;             // new_embeddings [2097152]
    float* outN   = outEmb + 2097152;           // new_N [8192]
    float* outM   = outN + 8192;                // new_m [2097152]

    // workspace (floats)
    float* ws      = (float*)d_ws;
    float* sums    = ws;                        // 2097152
    float* e2buf   = ws + 2097152;              // 8192
    float* x2buf   = e2buf + 8192;              // 16384
    u64*   best    = (u64*)(x2buf + 16384);     // 16384 u64
    int*   counts  = (int*)(best + 16384);      // 8192
    float* nsum    = (float*)(counts + 8192);   // 1

    // fp16 limbs + fp32 embT staged in output regions written later:
    f16* xhb = (f16*)out0;                      // 8 MB
    f16* xlb = xhb + 4194304;                   // 8 MB (out0 is 16 MB)
    f16* ehb = (f16*)outEmb;                    // 4 MB
    f16* elb = ehb + 2097152;                   // 4 MB (outEmb is 8 MB)
    float* embT = outM;                         // 8 MB, overwritten by vq_final last

    vq_x2split_kernel<<<4096, 256, 0, stream>>>(x, x2buf, xhb, xlb, sums, best);
    vq_trsplit_kernel<<<dim3(256, 8), 256, 0, stream>>>(emb, embT, ehb, elb);
    vq_e2_kernel<<<2048, 256, 0, stream>>>(embT, e2buf, counts, nsum);
    vq_argmin_kernel<<<dim3(KK / BN, TOK / BM), 256, 0, stream>>>(
        xhb, xlb, ehb, elb, x2buf, e2buf, best);
    vq_gs_kernel<<<4096, 256, 0, stream>>>(x, embT, best, out0, sums, counts);
    vq_newN_kernel<<<32, 256, 0, stream>>>(Nin, counts, outN, nsum);
    vq_final_kernel<<<8192, 256, 0, stream>>>(min, sums, outN, nsum, outEmb, outM);
}